// Round 2
// baseline (724.207 us; speedup 1.0000x reference)
//
#include <hip/hip_runtime.h>

#define N_NODES 100000
#define N_EDGES 1000000
#define D 64
#define SCAN_BLK 98   // ceil(100000/1024)

// ---------------- CSR build ----------------

__global__ void k_hist(const int* __restrict__ ei, int* __restrict__ deg) {
    int e = blockIdx.x * blockDim.x + threadIdx.x;
    if (e < N_EDGES) atomicAdd(&deg[ei[N_EDGES + e]], 1);
}

// phase 1: per-block (1024 elems) sums
__global__ void k_blocksum(const int* __restrict__ deg, int* __restrict__ bsum) {
    __shared__ int sdata[256];
    int t = threadIdx.x, b = blockIdx.x;
    int base = b * 1024 + t * 4;
    int s = 0;
#pragma unroll
    for (int i = 0; i < 4; i++) {
        int idx = base + i;
        if (idx < N_NODES) s += deg[idx];
    }
    sdata[t] = s;
    __syncthreads();
    for (int off = 128; off > 0; off >>= 1) {
        if (t < off) sdata[t] += sdata[t + off];
        __syncthreads();
    }
    if (t == 0) bsum[b] = sdata[0];
}

// phase 2: single small block scans the 98 block sums (exclusive, in place)
__global__ void k_scan_bsum(int* __restrict__ bsum, int nb, int* __restrict__ row_start) {
    __shared__ int tmp[128];
    int t = threadIdx.x;
    int v = (t < nb) ? bsum[t] : 0;
    tmp[t] = v;
    __syncthreads();
    for (int off = 1; off < 128; off <<= 1) {
        int add = (t >= off) ? tmp[t - off] : 0;
        __syncthreads();
        tmp[t] += add;
        __syncthreads();
    }
    int total = tmp[127];
    int excl = (t == 0) ? 0 : tmp[t - 1];
    if (t < nb) bsum[t] = excl;
    if (t == 0) row_start[N_NODES] = total;
}

// phase 3: per-block exclusive scan + offset; writes row_start, cursor, inv_cnt
__global__ void k_scan_write(const int* __restrict__ deg, const int* __restrict__ bsum,
                             int* __restrict__ row_start, int* __restrict__ cursor,
                             float* __restrict__ inv_cnt) {
    __shared__ int tmp[256];
    int t = threadIdx.x, b = blockIdx.x;
    int base = b * 1024 + t * 4;
    int local[4];
    int s = 0;
#pragma unroll
    for (int i = 0; i < 4; i++) {
        int idx = base + i;
        int d = (idx < N_NODES) ? deg[idx] : 0;
        local[i] = d;
        s += d;
    }
    tmp[t] = s;
    __syncthreads();
    for (int off = 1; off < 256; off <<= 1) {
        int add = (t >= off) ? tmp[t - off] : 0;
        __syncthreads();
        tmp[t] += add;
        __syncthreads();
    }
    int run = bsum[b] + ((t == 0) ? 0 : tmp[t - 1]);
#pragma unroll
    for (int i = 0; i < 4; i++) {
        int idx = base + i;
        if (idx < N_NODES) {
            row_start[idx] = run;
            cursor[idx] = run;
            int d = local[i];
            inv_cnt[idx] = 1.0f / (float)(d > 0 ? d : 1);
            run += d;
        }
    }
}

__global__ void k_scatter(const int* __restrict__ ei, int* __restrict__ cursor,
                          int* __restrict__ col) {
    int e = blockIdx.x * blockDim.x + threadIdx.x;
    if (e < N_EDGES) {
        int s = ei[e];
        int d = ei[N_EDGES + e];
        int p = atomicAdd(&cursor[d], 1);
        col[p] = s;
    }
}

// ---------------- aggregation: mean over in-neighbors ----------------
// 16 lanes per node (float4 per lane), 4 nodes per wave, edge loop unrolled x4:
// up to 16 independent gather chains in flight per wave.
__global__ void __launch_bounds__(256)
k_agg(const float4* __restrict__ X4, const int* __restrict__ row_start,
      const int* __restrict__ col, const float* __restrict__ inv_cnt,
      float4* __restrict__ M4) {
    int t = blockIdx.x * blockDim.x + threadIdx.x;
    int sub = t & 15;          // feature quad within node
    int n = t >> 4;            // node id
    if (n >= N_NODES) return;
    int s = row_start[n];
    int e = row_start[n + 1];
    float4 acc = make_float4(0.f, 0.f, 0.f, 0.f);
    int j = s;
    for (; j + 4 <= e; j += 4) {
        int c0 = col[j + 0];
        int c1 = col[j + 1];
        int c2 = col[j + 2];
        int c3 = col[j + 3];
        float4 a = X4[(size_t)c0 * 16 + sub];
        float4 b = X4[(size_t)c1 * 16 + sub];
        float4 c = X4[(size_t)c2 * 16 + sub];
        float4 d = X4[(size_t)c3 * 16 + sub];
        acc.x += (a.x + b.x) + (c.x + d.x);
        acc.y += (a.y + b.y) + (c.y + d.y);
        acc.z += (a.z + b.z) + (c.z + d.z);
        acc.w += (a.w + b.w) + (c.w + d.w);
    }
    for (; j < e; j++) {
        float4 a = X4[(size_t)col[j] * 16 + sub];
        acc.x += a.x; acc.y += a.y; acc.z += a.z; acc.w += a.w;
    }
    float ic = inv_cnt[n];
    acc.x *= ic; acc.y *= ic; acc.z *= ic; acc.w *= ic;
    M4[(size_t)n * 16 + sub] = acc;
}

// ---------------- fused linear: out = M*Wl^T + X*Wr^T + b (opt relu) -------------
// One THREAD per node: node's m[]/x[] rows live in VGPRs, weights are
// wave-uniform scalar operands (s_load) -> 1 VALU instr per FMA.
__global__ void __launch_bounds__(256)
k_linear(const float* __restrict__ Ma, const float* __restrict__ Xa,
         const float* __restrict__ Wl, const float* __restrict__ Wr,
         const float* __restrict__ bias, float* __restrict__ out, int do_relu) {
    int n = blockIdx.x * blockDim.x + threadIdx.x;
    if (n >= N_NODES) return;
    float m[D], x[D];
    const float4* M4 = (const float4*)(Ma + (size_t)n * D);
    const float4* X4 = (const float4*)(Xa + (size_t)n * D);
#pragma unroll
    for (int k4 = 0; k4 < D / 4; k4++) {
        float4 a = M4[k4];
        m[4 * k4 + 0] = a.x; m[4 * k4 + 1] = a.y;
        m[4 * k4 + 2] = a.z; m[4 * k4 + 3] = a.w;
        float4 b = X4[k4];
        x[4 * k4 + 0] = b.x; x[4 * k4 + 1] = b.y;
        x[4 * k4 + 2] = b.z; x[4 * k4 + 3] = b.w;
    }
    float4* O4 = (float4*)(out + (size_t)n * D);
    for (int oc = 0; oc < D; oc += 8) {
        float acc[8];
#pragma unroll
        for (int o = 0; o < 8; o++) acc[o] = bias[oc + o];
#pragma unroll
        for (int k = 0; k < D; k++) {
#pragma unroll
            for (int o = 0; o < 8; o++) {
                acc[o] = fmaf(m[k], Wl[(size_t)(oc + o) * D + k], acc[o]);
                acc[o] = fmaf(x[k], Wr[(size_t)(oc + o) * D + k], acc[o]);
            }
        }
        if (do_relu) {
#pragma unroll
            for (int o = 0; o < 8; o++) acc[o] = fmaxf(acc[o], 0.f);
        }
        float4 r0 = make_float4(acc[0], acc[1], acc[2], acc[3]);
        float4 r1 = make_float4(acc[4], acc[5], acc[6], acc[7]);
        O4[oc / 4 + 0] = r0;
        O4[oc / 4 + 1] = r1;
    }
}

// ---------------- launch ----------------
extern "C" void kernel_launch(void* const* d_in, const int* in_sizes, int n_in,
                              void* d_out, int out_size, void* d_ws, size_t ws_size,
                              hipStream_t stream) {
    const float* x   = (const float*)d_in[0];
    const int*   ei  = (const int*)d_in[1];
    const float* W1l = (const float*)d_in[2];
    const float* b1  = (const float*)d_in[3];
    const float* W1r = (const float*)d_in[4];
    const float* W2l = (const float*)d_in[5];
    const float* b2  = (const float*)d_in[6];
    const float* W2r = (const float*)d_in[7];
    float* out = (float*)d_out;

    char* ws = (char*)d_ws;
    size_t off = 0;
    auto alloc = [&](size_t bytes) -> char* {
        char* p = ws + off;
        off = (off + bytes + 255) & ~(size_t)255;
        return p;
    };
    int*   deg       = (int*)alloc((size_t)N_NODES * 4);
    int*   row_start = (int*)alloc((size_t)(N_NODES + 1) * 4);
    int*   cursor    = (int*)alloc((size_t)N_NODES * 4);
    int*   col       = (int*)alloc((size_t)N_EDGES * 4);
    float* invc      = (float*)alloc((size_t)N_NODES * 4);
    int*   bsum      = (int*)alloc(128 * 4);
    float* mbuf      = (float*)alloc((size_t)N_NODES * D * 4);
    float* hbuf      = (float*)alloc((size_t)N_NODES * D * 4);

    // CSR build (once; reused by both layers)
    hipMemsetAsync(deg, 0, (size_t)N_NODES * 4, stream);
    k_hist<<<(N_EDGES + 255) / 256, 256, 0, stream>>>(ei, deg);
    k_blocksum<<<SCAN_BLK, 256, 0, stream>>>(deg, bsum);
    k_scan_bsum<<<1, 128, 0, stream>>>(bsum, SCAN_BLK, row_start);
    k_scan_write<<<SCAN_BLK, 256, 0, stream>>>(deg, bsum, row_start, cursor, invc);
    k_scatter<<<(N_EDGES + 255) / 256, 256, 0, stream>>>(ei, cursor, col);

    const int agg_blocks = (N_NODES * 16 + 255) / 256;   // one 16-lane group per node
    const int lin_blocks = (N_NODES + 255) / 256;        // one thread per node

    // layer 1
    k_agg<<<agg_blocks, 256, 0, stream>>>((const float4*)x, row_start, col, invc,
                                          (float4*)mbuf);
    k_linear<<<lin_blocks, 256, 0, stream>>>(mbuf, x, W1l, W1r, b1, hbuf, 1);
    // layer 2
    k_agg<<<agg_blocks, 256, 0, stream>>>((const float4*)hbuf, row_start, col, invc,
                                          (float4*)mbuf);
    k_linear<<<lin_blocks, 256, 0, stream>>>(mbuf, hbuf, W2l, W2r, b2, out, 0);
}

// Round 3
// 613.194 us; speedup vs baseline: 1.1810x; 1.1810x over previous
//
#include <hip/hip_runtime.h>

#define N_NODES 100000
#define N_EDGES 1000000
#define D 64
#define SCAN_BLK 98   // ceil(100000/1024)

// ---------------- CSR build ----------------

__global__ void k_hist(const int* __restrict__ ei, int* __restrict__ deg) {
    int e = blockIdx.x * blockDim.x + threadIdx.x;
    if (e < N_EDGES) atomicAdd(&deg[ei[N_EDGES + e]], 1);
}

// phase 1: per-block (1024 elems) sums
__global__ void k_blocksum(const int* __restrict__ deg, int* __restrict__ bsum) {
    __shared__ int sdata[256];
    int t = threadIdx.x, b = blockIdx.x;
    int base = b * 1024 + t * 4;
    int s = 0;
#pragma unroll
    for (int i = 0; i < 4; i++) {
        int idx = base + i;
        if (idx < N_NODES) s += deg[idx];
    }
    sdata[t] = s;
    __syncthreads();
    for (int off = 128; off > 0; off >>= 1) {
        if (t < off) sdata[t] += sdata[t + off];
        __syncthreads();
    }
    if (t == 0) bsum[b] = sdata[0];
}

// phase 2: single small block scans the 98 block sums (exclusive, in place)
__global__ void k_scan_bsum(int* __restrict__ bsum, int nb, int* __restrict__ row_start) {
    __shared__ int tmp[128];
    int t = threadIdx.x;
    int v = (t < nb) ? bsum[t] : 0;
    tmp[t] = v;
    __syncthreads();
    for (int off = 1; off < 128; off <<= 1) {
        int add = (t >= off) ? tmp[t - off] : 0;
        __syncthreads();
        tmp[t] += add;
        __syncthreads();
    }
    int total = tmp[127];
    int excl = (t == 0) ? 0 : tmp[t - 1];
    if (t < nb) bsum[t] = excl;
    if (t == 0) row_start[N_NODES] = total;
}

// phase 3: per-block exclusive scan + offset; writes row_start, cursor, inv_cnt
__global__ void k_scan_write(const int* __restrict__ deg, const int* __restrict__ bsum,
                             int* __restrict__ row_start, int* __restrict__ cursor,
                             float* __restrict__ inv_cnt) {
    __shared__ int tmp[256];
    int t = threadIdx.x, b = blockIdx.x;
    int base = b * 1024 + t * 4;
    int local[4];
    int s = 0;
#pragma unroll
    for (int i = 0; i < 4; i++) {
        int idx = base + i;
        int d = (idx < N_NODES) ? deg[idx] : 0;
        local[i] = d;
        s += d;
    }
    tmp[t] = s;
    __syncthreads();
    for (int off = 1; off < 256; off <<= 1) {
        int add = (t >= off) ? tmp[t - off] : 0;
        __syncthreads();
        tmp[t] += add;
        __syncthreads();
    }
    int run = bsum[b] + ((t == 0) ? 0 : tmp[t - 1]);
#pragma unroll
    for (int i = 0; i < 4; i++) {
        int idx = base + i;
        if (idx < N_NODES) {
            row_start[idx] = run;
            cursor[idx] = run;
            int d = local[i];
            inv_cnt[idx] = 1.0f / (float)(d > 0 ? d : 1);
            run += d;
        }
    }
}

__global__ void k_scatter(const int* __restrict__ ei, int* __restrict__ cursor,
                          int* __restrict__ col) {
    int e = blockIdx.x * blockDim.x + threadIdx.x;
    if (e < N_EDGES) {
        int s = ei[e];
        int d = ei[N_EDGES + e];
        int p = atomicAdd(&cursor[d], 1);
        col[p] = s;
    }
}

// ---------------- aggregation: mean over in-neighbors ----------------
// 16 lanes per node (float4 per lane), 4 nodes per wave, edge loop unrolled x4:
// up to 16 independent gather chains in flight per wave.
__global__ void __launch_bounds__(256)
k_agg(const float4* __restrict__ X4, const int* __restrict__ row_start,
      const int* __restrict__ col, const float* __restrict__ inv_cnt,
      float4* __restrict__ M4) {
    int t = blockIdx.x * blockDim.x + threadIdx.x;
    int sub = t & 15;          // feature quad within node
    int n = t >> 4;            // node id
    if (n >= N_NODES) return;
    int s = row_start[n];
    int e = row_start[n + 1];
    float4 acc = make_float4(0.f, 0.f, 0.f, 0.f);
    int j = s;
    for (; j + 4 <= e; j += 4) {
        int c0 = col[j + 0];
        int c1 = col[j + 1];
        int c2 = col[j + 2];
        int c3 = col[j + 3];
        float4 a = X4[(size_t)c0 * 16 + sub];
        float4 b = X4[(size_t)c1 * 16 + sub];
        float4 c = X4[(size_t)c2 * 16 + sub];
        float4 d = X4[(size_t)c3 * 16 + sub];
        acc.x += (a.x + b.x) + (c.x + d.x);
        acc.y += (a.y + b.y) + (c.y + d.y);
        acc.z += (a.z + b.z) + (c.z + d.z);
        acc.w += (a.w + b.w) + (c.w + d.w);
    }
    for (; j < e; j++) {
        float4 a = X4[(size_t)col[j] * 16 + sub];
        acc.x += a.x; acc.y += a.y; acc.z += a.z; acc.w += a.w;
    }
    float ic = inv_cnt[n];
    acc.x *= ic; acc.y *= ic; acc.z *= ic; acc.w *= ic;
    M4[(size_t)n * 16 + sub] = acc;
}

// ---------------- fused linear: out = M*Wl^T + X*Wr^T + b (opt relu) -------------
// One THREAD per node. Output channels in chunks of 8; activation rows streamed
// as transient float4s (re-read per chunk from L1 -- 32KB/wave working set).
// Weights/bias are wave-uniform -> scalar loads, 1 VALU per FMA, no spills.
__global__ void __launch_bounds__(256)
k_linear(const float4* __restrict__ Ma4, const float4* __restrict__ Xa4,
         const float* __restrict__ Wl, const float* __restrict__ Wr,
         const float* __restrict__ bias, float4* __restrict__ out4, int do_relu) {
    int n = blockIdx.x * blockDim.x + threadIdx.x;
    if (n >= N_NODES) return;
    const float4* mrow = Ma4 + (size_t)n * (D / 4);
    const float4* xrow = Xa4 + (size_t)n * (D / 4);
#pragma unroll 1
    for (int oc = 0; oc < D; oc += 8) {
        float acc[8];
#pragma unroll
        for (int o = 0; o < 8; o++) acc[o] = bias[oc + o];
#pragma unroll
        for (int k4 = 0; k4 < D / 4; k4++) {
            float4 mv = mrow[k4];
            float4 xv = xrow[k4];
#pragma unroll
            for (int o = 0; o < 8; o++) {
                const float* wl = Wl + (size_t)(oc + o) * D + k4 * 4;
                const float* wr = Wr + (size_t)(oc + o) * D + k4 * 4;
                acc[o] = fmaf(mv.x, wl[0], acc[o]);
                acc[o] = fmaf(mv.y, wl[1], acc[o]);
                acc[o] = fmaf(mv.z, wl[2], acc[o]);
                acc[o] = fmaf(mv.w, wl[3], acc[o]);
                acc[o] = fmaf(xv.x, wr[0], acc[o]);
                acc[o] = fmaf(xv.y, wr[1], acc[o]);
                acc[o] = fmaf(xv.z, wr[2], acc[o]);
                acc[o] = fmaf(xv.w, wr[3], acc[o]);
            }
        }
        if (do_relu) {
#pragma unroll
            for (int o = 0; o < 8; o++) acc[o] = fmaxf(acc[o], 0.f);
        }
        float4 r0 = make_float4(acc[0], acc[1], acc[2], acc[3]);
        float4 r1 = make_float4(acc[4], acc[5], acc[6], acc[7]);
        out4[(size_t)n * (D / 4) + oc / 4 + 0] = r0;
        out4[(size_t)n * (D / 4) + oc / 4 + 1] = r1;
    }
}

// ---------------- launch ----------------
extern "C" void kernel_launch(void* const* d_in, const int* in_sizes, int n_in,
                              void* d_out, int out_size, void* d_ws, size_t ws_size,
                              hipStream_t stream) {
    const float* x   = (const float*)d_in[0];
    const int*   ei  = (const int*)d_in[1];
    const float* W1l = (const float*)d_in[2];
    const float* b1  = (const float*)d_in[3];
    const float* W1r = (const float*)d_in[4];
    const float* W2l = (const float*)d_in[5];
    const float* b2  = (const float*)d_in[6];
    const float* W2r = (const float*)d_in[7];
    float* out = (float*)d_out;

    char* ws = (char*)d_ws;
    size_t off = 0;
    auto alloc = [&](size_t bytes) -> char* {
        char* p = ws + off;
        off = (off + bytes + 255) & ~(size_t)255;
        return p;
    };
    int*   deg       = (int*)alloc((size_t)N_NODES * 4);
    int*   row_start = (int*)alloc((size_t)(N_NODES + 1) * 4);
    int*   cursor    = (int*)alloc((size_t)N_NODES * 4);
    int*   col       = (int*)alloc((size_t)N_EDGES * 4);
    float* invc      = (float*)alloc((size_t)N_NODES * 4);
    int*   bsum      = (int*)alloc(128 * 4);
    float* mbuf      = (float*)alloc((size_t)N_NODES * D * 4);
    float* hbuf      = (float*)alloc((size_t)N_NODES * D * 4);

    // CSR build (once; reused by both layers)
    hipMemsetAsync(deg, 0, (size_t)N_NODES * 4, stream);
    k_hist<<<(N_EDGES + 255) / 256, 256, 0, stream>>>(ei, deg);
    k_blocksum<<<SCAN_BLK, 256, 0, stream>>>(deg, bsum);
    k_scan_bsum<<<1, 128, 0, stream>>>(bsum, SCAN_BLK, row_start);
    k_scan_write<<<SCAN_BLK, 256, 0, stream>>>(deg, bsum, row_start, cursor, invc);
    k_scatter<<<(N_EDGES + 255) / 256, 256, 0, stream>>>(ei, cursor, col);

    const int agg_blocks = (N_NODES * 16 + 255) / 256;   // one 16-lane group per node
    const int lin_blocks = (N_NODES + 255) / 256;        // one thread per node

    // layer 1
    k_agg<<<agg_blocks, 256, 0, stream>>>((const float4*)x, row_start, col, invc,
                                          (float4*)mbuf);
    k_linear<<<lin_blocks, 256, 0, stream>>>((const float4*)mbuf, (const float4*)x,
                                             W1l, W1r, b1, (float4*)hbuf, 1);
    // layer 2
    k_agg<<<agg_blocks, 256, 0, stream>>>((const float4*)hbuf, row_start, col, invc,
                                          (float4*)mbuf);
    k_linear<<<lin_blocks, 256, 0, stream>>>((const float4*)mbuf, (const float4*)hbuf,
                                             W2l, W2r, b2, (float4*)out, 0);
}

// Round 4
// 362.707 us; speedup vs baseline: 1.9967x; 1.6906x over previous
//
#include <hip/hip_runtime.h>

#define N_NODES 100000
#define N_EDGES 1000000
#define D 64
#define SCAN_BLK 98   // ceil(100000/1024)
#define WROW 68       // LDS row stride (floats): 16B-aligned, breaks bank conflicts

// ---------------- CSR build ----------------

__global__ void k_hist(const int* __restrict__ ei, int* __restrict__ deg) {
    int e = blockIdx.x * blockDim.x + threadIdx.x;
    if (e < N_EDGES) atomicAdd(&deg[ei[N_EDGES + e]], 1);
}

__global__ void k_blocksum(const int* __restrict__ deg, int* __restrict__ bsum) {
    __shared__ int sdata[256];
    int t = threadIdx.x, b = blockIdx.x;
    int base = b * 1024 + t * 4;
    int s = 0;
#pragma unroll
    for (int i = 0; i < 4; i++) {
        int idx = base + i;
        if (idx < N_NODES) s += deg[idx];
    }
    sdata[t] = s;
    __syncthreads();
    for (int off = 128; off > 0; off >>= 1) {
        if (t < off) sdata[t] += sdata[t + off];
        __syncthreads();
    }
    if (t == 0) bsum[b] = sdata[0];
}

__global__ void k_scan_bsum(int* __restrict__ bsum, int nb, int* __restrict__ row_start) {
    __shared__ int tmp[128];
    int t = threadIdx.x;
    int v = (t < nb) ? bsum[t] : 0;
    tmp[t] = v;
    __syncthreads();
    for (int off = 1; off < 128; off <<= 1) {
        int add = (t >= off) ? tmp[t - off] : 0;
        __syncthreads();
        tmp[t] += add;
        __syncthreads();
    }
    int total = tmp[127];
    int excl = (t == 0) ? 0 : tmp[t - 1];
    if (t < nb) bsum[t] = excl;
    if (t == 0) row_start[N_NODES] = total;
}

__global__ void k_scan_write(const int* __restrict__ deg, const int* __restrict__ bsum,
                             int* __restrict__ row_start, int* __restrict__ cursor,
                             float* __restrict__ inv_cnt) {
    __shared__ int tmp[256];
    int t = threadIdx.x, b = blockIdx.x;
    int base = b * 1024 + t * 4;
    int local[4];
    int s = 0;
#pragma unroll
    for (int i = 0; i < 4; i++) {
        int idx = base + i;
        int d = (idx < N_NODES) ? deg[idx] : 0;
        local[i] = d;
        s += d;
    }
    tmp[t] = s;
    __syncthreads();
    for (int off = 1; off < 256; off <<= 1) {
        int add = (t >= off) ? tmp[t - off] : 0;
        __syncthreads();
        tmp[t] += add;
        __syncthreads();
    }
    int run = bsum[b] + ((t == 0) ? 0 : tmp[t - 1]);
#pragma unroll
    for (int i = 0; i < 4; i++) {
        int idx = base + i;
        if (idx < N_NODES) {
            row_start[idx] = run;
            cursor[idx] = run;
            int d = local[i];
            inv_cnt[idx] = 1.0f / (float)(d > 0 ? d : 1);
            run += d;
        }
    }
}

__global__ void k_scatter(const int* __restrict__ ei, int* __restrict__ cursor,
                          int* __restrict__ col) {
    int e = blockIdx.x * blockDim.x + threadIdx.x;
    if (e < N_EDGES) {
        int s = ei[e];
        int d = ei[N_EDGES + e];
        int p = atomicAdd(&cursor[d], 1);
        col[p] = s;
    }
}

// ---------------- aggregation: mean over in-neighbors ----------------
__global__ void __launch_bounds__(256)
k_agg(const float4* __restrict__ X4, const int* __restrict__ row_start,
      const int* __restrict__ col, const float* __restrict__ inv_cnt,
      float4* __restrict__ M4) {
    int t = blockIdx.x * blockDim.x + threadIdx.x;
    int sub = t & 15;          // feature quad within node
    int n = t >> 4;            // node id
    if (n >= N_NODES) return;
    int s = row_start[n];
    int e = row_start[n + 1];
    float4 acc = make_float4(0.f, 0.f, 0.f, 0.f);
    int j = s;
    for (; j + 4 <= e; j += 4) {
        int c0 = col[j + 0];
        int c1 = col[j + 1];
        int c2 = col[j + 2];
        int c3 = col[j + 3];
        float4 a = X4[(size_t)c0 * 16 + sub];
        float4 b = X4[(size_t)c1 * 16 + sub];
        float4 c = X4[(size_t)c2 * 16 + sub];
        float4 d = X4[(size_t)c3 * 16 + sub];
        acc.x += (a.x + b.x) + (c.x + d.x);
        acc.y += (a.y + b.y) + (c.y + d.y);
        acc.z += (a.z + b.z) + (c.z + d.z);
        acc.w += (a.w + b.w) + (c.w + d.w);
    }
    for (; j < e; j++) {
        float4 a = X4[(size_t)col[j] * 16 + sub];
        acc.x += a.x; acc.y += a.y; acc.z += a.z; acc.w += a.w;
    }
    float ic = inv_cnt[n];
    acc.x *= ic; acc.y *= ic; acc.z *= ic; acc.w *= ic;
    M4[(size_t)n * 16 + sub] = acc;
}

// ---------------- fused linear: out = M*Wl^T + X*Wr^T + b (opt relu) -------------
// lane = node (64 nodes/block), wave = 16 output channels (4 waves cover 64 oc).
// Weights staged in LDS transposed (k-major, row stride 68 floats): every weight
// read is a wave-uniform ds_read_b128 -> broadcast, zero conflicts.
// Register pressure bounded: acc[16] + 2 transient float4 + weight frags.
__global__ void __launch_bounds__(256)
k_linear(const float4* __restrict__ Ma4, const float4* __restrict__ Xa4,
         const float* __restrict__ Wl, const float* __restrict__ Wr,
         const float* __restrict__ bias, float4* __restrict__ out4, int do_relu) {
    __shared__ float wlT[D * WROW];
    __shared__ float wrT[D * WROW];
    int t = threadIdx.x;
    // stage transposed weights: wlT[k*WROW + oc] = Wl[oc*D + k]
    for (int i = t; i < D * D; i += 256) {
        int oc = i >> 6, k = i & 63;
        wlT[k * WROW + oc] = Wl[i];
        wrT[k * WROW + oc] = Wr[i];
    }
    __syncthreads();

    int lane = t & 63;
    int ocb = (t >> 6) * 16;                // this wave's output-channel base
    int n = blockIdx.x * 64 + lane;
    if (n >= N_NODES) return;               // no barriers after this point

    const float4* mrow = Ma4 + (size_t)n * (D / 4);
    const float4* xrow = Xa4 + (size_t)n * (D / 4);

    float acc[16];
#pragma unroll
    for (int o = 0; o < 16; o++) acc[o] = bias[ocb + o];

#pragma unroll 4
    for (int k4 = 0; k4 < D / 4; k4++) {
        float4 mv = mrow[k4];
        float4 xv = xrow[k4];
        const float* mp = (const float*)&mv;
        const float* xp = (const float*)&xv;
#pragma unroll
        for (int j = 0; j < 4; j++) {
            int k = k4 * 4 + j;
            const float4* wl4 = (const float4*)&wlT[k * WROW + ocb];
            const float4* wr4 = (const float4*)&wrT[k * WROW + ocb];
            float mj = mp[j];
            float xj = xp[j];
#pragma unroll
            for (int og = 0; og < 4; og++) {
                float4 wlv = wl4[og];
                float4 wrv = wr4[og];
                acc[og * 4 + 0] = fmaf(mj, wlv.x, fmaf(xj, wrv.x, acc[og * 4 + 0]));
                acc[og * 4 + 1] = fmaf(mj, wlv.y, fmaf(xj, wrv.y, acc[og * 4 + 1]));
                acc[og * 4 + 2] = fmaf(mj, wlv.z, fmaf(xj, wrv.z, acc[og * 4 + 2]));
                acc[og * 4 + 3] = fmaf(mj, wlv.w, fmaf(xj, wrv.w, acc[og * 4 + 3]));
            }
        }
    }

    if (do_relu) {
#pragma unroll
        for (int o = 0; o < 16; o++) acc[o] = fmaxf(acc[o], 0.f);
    }
    float4* orow = out4 + (size_t)n * (D / 4) + ocb / 4;
#pragma unroll
    for (int og = 0; og < 4; og++) {
        orow[og] = make_float4(acc[og * 4 + 0], acc[og * 4 + 1],
                               acc[og * 4 + 2], acc[og * 4 + 3]);
    }
}

// ---------------- launch ----------------
extern "C" void kernel_launch(void* const* d_in, const int* in_sizes, int n_in,
                              void* d_out, int out_size, void* d_ws, size_t ws_size,
                              hipStream_t stream) {
    const float* x   = (const float*)d_in[0];
    const int*   ei  = (const int*)d_in[1];
    const float* W1l = (const float*)d_in[2];
    const float* b1  = (const float*)d_in[3];
    const float* W1r = (const float*)d_in[4];
    const float* W2l = (const float*)d_in[5];
    const float* b2  = (const float*)d_in[6];
    const float* W2r = (const float*)d_in[7];
    float* out = (float*)d_out;

    char* ws = (char*)d_ws;
    size_t off = 0;
    auto alloc = [&](size_t bytes) -> char* {
        char* p = ws + off;
        off = (off + bytes + 255) & ~(size_t)255;
        return p;
    };
    int*   deg       = (int*)alloc((size_t)N_NODES * 4);
    int*   row_start = (int*)alloc((size_t)(N_NODES + 1) * 4);
    int*   cursor    = (int*)alloc((size_t)N_NODES * 4);
    int*   col       = (int*)alloc((size_t)N_EDGES * 4);
    float* invc      = (float*)alloc((size_t)N_NODES * 4);
    int*   bsum      = (int*)alloc(128 * 4);
    float* mbuf      = (float*)alloc((size_t)N_NODES * D * 4);
    float* hbuf      = (float*)alloc((size_t)N_NODES * D * 4);

    // CSR build (once; reused by both layers)
    hipMemsetAsync(deg, 0, (size_t)N_NODES * 4, stream);
    k_hist<<<(N_EDGES + 255) / 256, 256, 0, stream>>>(ei, deg);
    k_blocksum<<<SCAN_BLK, 256, 0, stream>>>(deg, bsum);
    k_scan_bsum<<<1, 128, 0, stream>>>(bsum, SCAN_BLK, row_start);
    k_scan_write<<<SCAN_BLK, 256, 0, stream>>>(deg, bsum, row_start, cursor, invc);
    k_scatter<<<(N_EDGES + 255) / 256, 256, 0, stream>>>(ei, cursor, col);

    const int agg_blocks = (N_NODES * 16 + 255) / 256;   // 16 lanes per node
    const int lin_blocks = (N_NODES + 63) / 64;          // 64 nodes per block

    // layer 1
    k_agg<<<agg_blocks, 256, 0, stream>>>((const float4*)x, row_start, col, invc,
                                          (float4*)mbuf);
    k_linear<<<lin_blocks, 256, 0, stream>>>((const float4*)mbuf, (const float4*)x,
                                             W1l, W1r, b1, (float4*)hbuf, 1);
    // layer 2
    k_agg<<<agg_blocks, 256, 0, stream>>>((const float4*)hbuf, row_start, col, invc,
                                          (float4*)mbuf);
    k_linear<<<lin_blocks, 256, 0, stream>>>((const float4*)mbuf, (const float4*)hbuf,
                                             W2l, W2r, b2, (float4*)out, 0);
}